// Round 8
// baseline (430.506 us; speedup 1.0000x reference)
//
#include <hip/hip_runtime.h>
#include <math.h>

// R19: INSTRUMENTED ROUND (R18 kernel unchanged + one ablation probe).
// Evidence R12/R13/R14/R15/R18: per-CU time for 128 px-rows is ~42-46us,
// invariant to A-traffic (x0.5/x1/x2), A-latency structure (LDS ring +
// counted vmcnt), LDS B-read volume (x0.5), waves/CU (6->32), rounds (2->1).
// Bottom-up pipe accounting says <=20us -> model missing ~2x; counters
// aggregate conv+routing so they can't locate it. Probe: same kernel,
// conv phase repeated 3x, routing removed (acc kept live via asm, rule #17),
// no stores. Probe dur D in top-5 => conv = (D-2)/3; absent => conv < 14us
// => routing chain is the wall. R16's earlier split was confounded by a
// 131MB HBM votes round-trip; this probe has no extra memory traffic.
// NOTE: hipLaunchCooperativeKernel is NOT graph-capturable here (R7 failed);
// ~44us d_ws re-poison fill + ~12us restore/launch are fixed harness overhead.
//
// x:    [B=32][H=32][W=32][128] fp32 (128 = i*16+cin)
// wts:  [i=8][k=144][o=128] fp32 -> w16[(i*5+q)][c][lane][j]
//       = wts[(i*144 + q*32 + (lane>>4)*8 + j)*128 + c*16 + (lane&15)], 0 for k>=144
// out:  [B][H][W][128] fp32 (o = c*16+f)
//
// Block = 1024 = 16 waves; wave w: c = w&7, g = w>>3; 2 rows x 32 px.
// Grid = 512 (b*16 + h2), h = 2*h2. Slot s = g*32 + mt*16 + l15 (0..63).
// MFMA 16x16x32: A[m=lane&15 -> f][k=quad*8+j], B[k][n=lane&15 -> px(mt)].

typedef _Float16 fp16x8 __attribute__((ext_vector_type(8)));
typedef float f32x4 __attribute__((ext_vector_type(4)));

#define EPS 1e-7f
constexpr int PSTRIDE = 136;   // fp16 elems; 272B row stride: 16B-aligned, 2-way banks (free)
constexpr int PCOLS   = 34;    // 32 px + 2 halo
constexpr int PROWS   = 4;     // rows h-1..h+2
constexpr int LSTRIDE = 76;    // lg_arr: [slot*76 + i*9 + c]
constexpr int PXS     = 76;    // r_arr:  [slot*76 + c*8 + i]; b128 stride 304B -> 2-way (free)
constexpr int W_ELEMS = 40 * 8 * 64 * 8;   // 163840

// sum across the 4 quads (lanes ^16, ^32); all lanes receive the total
__device__ __forceinline__ float sumquad(float v) {
    v += __shfl_xor(v, 16);
    v += __shfl_xor(v, 32);
    return v;
}

// prep: direct scatter, 640 blocks x 256 threads, 1 element each (R8-proven).
__global__ __launch_bounds__(256)
void prep_weights(const float* __restrict__ wts,
                  _Float16* __restrict__ w16) {
    int n = blockIdx.x * 256 + threadIdx.x;        // 0..163839
    if (n >= W_ELEMS) return;
    int j    = n & 7;
    int ln   = (n >> 3) & 63;
    int c0   = (n >> 9) & 7;
    int iq   = n >> 12;                            // i*5+q
    int i0   = iq / 5;
    int q0   = iq - i0 * 5;
    int k = q0 * 32 + (ln >> 4) * 8 + j;
    float w = 0.f;
    if (k < 144) w = wts[(i0 * 144 + k) * 128 + c0 * 16 + (ln & 15)];
    w16[n] = (_Float16)w;                          // RNE
}

// MODE 0 = real kernel (1x conv + routing -> out).
// MODE 1 = probe: 3x conv, acc kept live, routing skipped, NO stores.
template<int MODE>
__global__ __launch_bounds__(1024, 4)
void capsule_mfma_kernel(const float* __restrict__ x,
                         const _Float16* __restrict__ w16,
                         const float* __restrict__ bias,
                         float* __restrict__ out)
{
    __shared__ _Float16 patch[PROWS * PCOLS * PSTRIDE];  // 36992 B
    __shared__ float lg_arr[64 * LSTRIDE];               // 19456 B
    __shared__ float r_arr[64 * PXS];                    // 19456 B

    const int tid  = threadIdx.x;
    const int lane = tid & 63;
    const int w    = tid >> 6;     // 0..15
    const int c    = w & 7;        // output capsule
    const int g    = w >> 3;       // output row offset (0/1)
    const int l15  = lane & 15;    // A: f ; B & D: px-in-tile
    const int quad = lane >> 4;
    const int lane8 = lane * 8;

    const int bid = blockIdx.x;
    const int h2 = bid & 15, b = bid >> 4;
    const int h = h2 << 1;         // output rows h, h+1

    // ---- stage input patch rows h-1..h+2, cols -1..32, fp16 ----
    const float4* x4 = (const float4*)x;
    for (int idx = tid; idx < PROWS * PCOLS * 32; idx += 1024) {
        int ch4  = idx & 31;
        int slot = idx >> 5;               // row*34 + colp
        int row  = slot / PCOLS;
        int colp = slot - row * PCOLS;
        int gh = h - 1 + row;
        int gw = colp - 1;
        float4 v = {0.f, 0.f, 0.f, 0.f};
        if ((unsigned)gh < 32u && (unsigned)gw < 32u)
            v = x4[(((b * 32 + gh) * 32 + gw) << 5) + ch4];
        _Float16 ph[4];
        ph[0] = (_Float16)v.x; ph[1] = (_Float16)v.y;
        ph[2] = (_Float16)v.z; ph[3] = (_Float16)v.w;
        *(ushort4*)&patch[slot * PSTRIDE + ch4 * 4] = *(const ushort4*)ph;
    }
    __syncthreads();

    // ---- B (patch) per-lane offsets: k = q*32 + quad*8 + j; tap = 2q+(quad>>1) ----
    int a_off[5];
    #pragma unroll
    for (int q = 0; q < 5; ++q) {
        int tap = 2 * q + (quad >> 1);
        if (tap > 8) tap = 8;                 // pad region: A is zero there
        int dy = tap / 3, dx = tap - dy * 3;
        a_off[q] = ((g + dy) * PCOLS + l15 + dx) * PSTRIDE + (quad & 1) * 8;
    }

    // ---- conv via MFMA: 40 steps of (1 A b128 from L1/L2, 2 B ds_read, 2 MFMA) ----
    f32x4 acc[2][8];
    #pragma unroll
    for (int mt = 0; mt < 2; ++mt)
        #pragma unroll
        for (int i = 0; i < 8; ++i) acc[mt][i] = (f32x4){0.f, 0.f, 0.f, 0.f};

    for (int rep = 0; rep < (MODE == 1 ? 3 : 1); ++rep) {
        #pragma unroll
        for (int q = 0; q < 5; ++q) {
            #pragma unroll
            for (int i = 0; i < 8; ++i) {
                int woff = ((i * 5 + q) * 8 + c) * 512 + lane8;
                fp16x8 aw = *(const fp16x8*)(w16 + woff);
                fp16x8 b0 = *(const fp16x8*)(patch + a_off[q] + i * 16);
                fp16x8 b1 = *(const fp16x8*)(patch + a_off[q] + 16 * PSTRIDE + i * 16);
                acc[0][i] = __builtin_amdgcn_mfma_f32_16x16x32_f16(aw, b0, acc[0][i], 0, 0, 0);
                acc[1][i] = __builtin_amdgcn_mfma_f32_16x16x32_f16(aw, b1, acc[1][i], 0, 0, 0);
            }
        }
    }

    if constexpr (MODE == 1) {
        // keep every MFMA live (rule #17: ablation-via-skip DCEs upstream ops)
        float keep = 0.f;
        #pragma unroll
        for (int mt = 0; mt < 2; ++mt)
            #pragma unroll
            for (int i = 0; i < 8; ++i)
                keep += acc[mt][i][0] + acc[mt][i][1] + acc[mt][i][2] + acc[mt][i][3];
        asm volatile("" :: "v"(keep));
        return;
    }

    // ---- dynamic routing: thread owns (slot = g*32+mt*16+l15, c, f = quad*4+0..3) ----
    const float4 bb4 = *(const float4*)(bias + c * 16 + quad * 4);
    const float barr[4] = {bb4.x, bb4.y, bb4.z, bb4.w};

    float actv[2][4];

    // iter 0: route = 1/8 uniform
    #pragma unroll
    for (int mt = 0; mt < 2; ++mt) {
        float pre[4];
        #pragma unroll
        for (int r = 0; r < 4; ++r) {
            float s = acc[mt][0][r] + acc[mt][1][r] + acc[mt][2][r] + acc[mt][3][r]
                    + acc[mt][4][r] + acc[mt][5][r] + acc[mt][6][r] + acc[mt][7][r];
            pre[r] = s * 0.125f + barr[r];
        }
        float s2 = sumquad(pre[0]*pre[0] + pre[1]*pre[1] + pre[2]*pre[2] + pre[3]*pre[3]);
        float scale = s2 * __builtin_amdgcn_rsqf(s2 + EPS) * __builtin_amdgcn_rcpf(1.f + s2);
        #pragma unroll
        for (int r = 0; r < 4; ++r) actv[mt][r] = scale * pre[r];
    }
    #pragma unroll
    for (int mt = 0; mt < 2; ++mt) {
        int slot = g * 32 + mt * 16 + l15;
        #pragma unroll
        for (int i = 0; i < 8; ++i) {
            float t = acc[mt][i][0]*actv[mt][0] + acc[mt][i][1]*actv[mt][1]
                    + acc[mt][i][2]*actv[mt][2] + acc[mt][i][3]*actv[mt][3];
            t = sumquad(t);
            if (quad == 0) lg_arr[slot * LSTRIDE + i * 9 + c] = t;
        }
    }
    __syncthreads();
    if (tid < 512) {   // softmax over c for each (slot, i): 64*8 = 512 tasks
        int p = tid >> 3, ii = tid & 7;
        const float* lrow = &lg_arr[p * LSTRIDE + ii * 9];
        float m = lrow[0];
        #pragma unroll
        for (int cc = 1; cc < 8; ++cc) m = fmaxf(m, lrow[cc]);
        float e[8]; float den = 0.f;
        #pragma unroll
        for (int cc = 0; cc < 8; ++cc) { e[cc] = __expf(lrow[cc] - m); den += e[cc]; }
        float rd = __builtin_amdgcn_rcpf(den);
        #pragma unroll
        for (int cc = 0; cc < 8; ++cc) r_arr[p * PXS + cc * 8 + ii] = e[cc] * rd;
    }
    __syncthreads();

    // iter 1
    #pragma unroll
    for (int mt = 0; mt < 2; ++mt) {
        int slot = g * 32 + mt * 16 + l15;
        const float4* rp = (const float4*)&r_arr[slot * PXS + c * 8];
        float4 r0 = rp[0], r1 = rp[1];
        float pre[4];
        #pragma unroll
        for (int r = 0; r < 4; ++r) {
            float s;
            s  = r0.x * acc[mt][0][r]; s = fmaf(r0.y, acc[mt][1][r], s);
            s  = fmaf(r0.z, acc[mt][2][r], s); s = fmaf(r0.w, acc[mt][3][r], s);
            s  = fmaf(r1.x, acc[mt][4][r], s); s = fmaf(r1.y, acc[mt][5][r], s);
            s  = fmaf(r1.z, acc[mt][6][r], s); s = fmaf(r1.w, acc[mt][7][r], s);
            pre[r] = s + barr[r];
        }
        float s2 = sumquad(pre[0]*pre[0] + pre[1]*pre[1] + pre[2]*pre[2] + pre[3]*pre[3]);
        float scale = s2 * __builtin_amdgcn_rsqf(s2 + EPS) * __builtin_amdgcn_rcpf(1.f + s2);
        #pragma unroll
        for (int r = 0; r < 4; ++r) actv[mt][r] = scale * pre[r];
    }
    #pragma unroll
    for (int mt = 0; mt < 2; ++mt) {
        int slot = g * 32 + mt * 16 + l15;
        #pragma unroll
        for (int i = 0; i < 8; ++i) {
            float t = acc[mt][i][0]*actv[mt][0] + acc[mt][i][1]*actv[mt][1]
                    + acc[mt][i][2]*actv[mt][2] + acc[mt][i][3]*actv[mt][3];
            t = sumquad(t);
            if (quad == 0) lg_arr[slot * LSTRIDE + i * 9 + c] += t;
        }
    }
    __syncthreads();
    if (tid < 512) {
        int p = tid >> 3, ii = tid & 7;
        const float* lrow = &lg_arr[p * LSTRIDE + ii * 9];
        float m = lrow[0];
        #pragma unroll
        for (int cc = 1; cc < 8; ++cc) m = fmaxf(m, lrow[cc]);
        float e[8]; float den = 0.f;
        #pragma unroll
        for (int cc = 0; cc < 8; ++cc) { e[cc] = __expf(lrow[cc] - m); den += e[cc]; }
        float rd = __builtin_amdgcn_rcpf(den);
        #pragma unroll
        for (int cc = 0; cc < 8; ++cc) r_arr[p * PXS + cc * 8 + ii] = e[cc] * rd;
    }
    __syncthreads();

    // iter 2: final activation -> out (per-lane float4: f = quad*4 + 0..3)
    #pragma unroll
    for (int mt = 0; mt < 2; ++mt) {
        int slot = g * 32 + mt * 16 + l15;
        const float4* rp = (const float4*)&r_arr[slot * PXS + c * 8];
        float4 r0 = rp[0], r1 = rp[1];
        float pre[4];
        #pragma unroll
        for (int r = 0; r < 4; ++r) {
            float s;
            s  = r0.x * acc[mt][0][r]; s = fmaf(r0.y, acc[mt][1][r], s);
            s  = fmaf(r0.z, acc[mt][2][r], s); s = fmaf(r0.w, acc[mt][3][r], s);
            s  = fmaf(r1.x, acc[mt][4][r], s); s = fmaf(r1.y, acc[mt][5][r], s);
            s  = fmaf(r1.z, acc[mt][6][r], s); s = fmaf(r1.w, acc[mt][7][r], s);
            pre[r] = s + barr[r];
        }
        float s2 = sumquad(pre[0]*pre[0] + pre[1]*pre[1] + pre[2]*pre[2] + pre[3]*pre[3]);
        float scale = s2 * __builtin_amdgcn_rsqf(s2 + EPS) * __builtin_amdgcn_rcpf(1.f + s2);
        float4 o4 = { scale*pre[0], scale*pre[1], scale*pre[2], scale*pre[3] };
        int gh = h + g;
        int px = mt * 16 + l15;
        *(float4*)(out + (((b * 32 + gh) * 32 + px) << 7) + c * 16 + quad * 4) = o4;
    }
}

extern "C" void kernel_launch(void* const* d_in, const int* in_sizes, int n_in,
                              void* d_out, int out_size, void* d_ws, size_t ws_size,
                              hipStream_t stream) {
    const float* x    = (const float*)d_in[0];
    const float* wts  = (const float*)d_in[1];
    const float* bias = (const float*)d_in[2];
    float* out        = (float*)d_out;
    _Float16* w16     = (_Float16*)d_ws;

    prep_weights<<<dim3(640), dim3(256), 0, stream>>>(wts, w16);
    capsule_mfma_kernel<0><<<dim3(512), dim3(1024), 0, stream>>>(x, w16, bias, out);
    // probe: 3x conv, no routing, no stores (dur read from rocprof top-5)
    capsule_mfma_kernel<1><<<dim3(512), dim3(1024), 0, stream>>>(x, w16, bias, out);
}

// Round 9
// 344.437 us; speedup vs baseline: 1.2499x; 1.2499x over previous
//
#include <hip/hip_runtime.h>
#include <math.h>

// R20: CLEAN PROBE ROUND. R19's template<3x-unroll> probe spilled (745MB
// scratch writes, 397MB fetch) -> measured a different kernel (rule #19/#20).
// This round: ONE kernel, ONE compilation, runtime `mode` flag (uniform SGPR
// branch -> identical codegen for all dispatches). bit0 = staging+conv,
// bit1 = routing+store. Probes run 8x-replicated (grid 4096, bid&511) so
// both exceed the 44us fills and appear in rocprof top-5:
//   probe A (mode=1): dur = 8 x (staging+conv)
//   probe B (mode=2): dur = 8 x (routing), acc=0 (finite: squash(bias)),
//                     writes overwritten by the real kernel afterwards.
//   real   (mode=3, grid 512): unchanged R18 kernel, runs LAST -> correct out.
// Decision rule (pre-committed): D_A/8 >= 25us -> conv wall -> R21 c-pair
// one-round; D_B/8 >= 20us -> routing wall -> R21 LDS-batched quad-reduce.
// VGPR_Count equality across dispatches = codegen-integrity check.
// NOTE: hipLaunchCooperativeKernel is NOT graph-capturable here (R7 failed);
// ~44us d_ws re-poison fill + ~12us restore/launch are fixed harness overhead.
//
// x:    [B=32][H=32][W=32][128] fp32 (128 = i*16+cin)
// wts:  [i=8][k=144][o=128] fp32 -> w16[(i*5+q)][c][lane][j]
//       = wts[(i*144 + q*32 + (lane>>4)*8 + j)*128 + c*16 + (lane&15)], 0 for k>=144
// out:  [B][H][W][128] fp32 (o = c*16+f)
//
// Block = 1024 = 16 waves; wave w: c = w&7, g = w>>3; 2 rows x 32 px.
// Grid = 512 (b*16 + h2), h = 2*h2. Slot s = g*32 + mt*16 + l15 (0..63).
// MFMA 16x16x32: A[m=lane&15 -> f][k=quad*8+j], B[k][n=lane&15 -> px(mt)].

typedef _Float16 fp16x8 __attribute__((ext_vector_type(8)));
typedef float f32x4 __attribute__((ext_vector_type(4)));

#define EPS 1e-7f
constexpr int PSTRIDE = 136;   // fp16 elems; 272B row stride: 16B-aligned, 2-way banks (free)
constexpr int PCOLS   = 34;    // 32 px + 2 halo
constexpr int PROWS   = 4;     // rows h-1..h+2
constexpr int LSTRIDE = 76;    // lg_arr: [slot*76 + i*9 + c]
constexpr int PXS     = 76;    // r_arr:  [slot*76 + c*8 + i]; b128 stride 304B -> 2-way (free)
constexpr int W_ELEMS = 40 * 8 * 64 * 8;   // 163840

// sum across the 4 quads (lanes ^16, ^32); all lanes receive the total
__device__ __forceinline__ float sumquad(float v) {
    v += __shfl_xor(v, 16);
    v += __shfl_xor(v, 32);
    return v;
}

// prep: direct scatter, 640 blocks x 256 threads, 1 element each (R8-proven).
__global__ __launch_bounds__(256)
void prep_weights(const float* __restrict__ wts,
                  _Float16* __restrict__ w16) {
    int n = blockIdx.x * 256 + threadIdx.x;        // 0..163839
    if (n >= W_ELEMS) return;
    int j    = n & 7;
    int ln   = (n >> 3) & 63;
    int c0   = (n >> 9) & 7;
    int iq   = n >> 12;                            // i*5+q
    int i0   = iq / 5;
    int q0   = iq - i0 * 5;
    int k = q0 * 32 + (ln >> 4) * 8 + j;
    float w = 0.f;
    if (k < 144) w = wts[(i0 * 144 + k) * 128 + c0 * 16 + (ln & 15)];
    w16[n] = (_Float16)w;                          // RNE
}

__global__ __launch_bounds__(1024, 4)
void capsule_mfma_kernel(const float* __restrict__ x,
                         const _Float16* __restrict__ w16,
                         const float* __restrict__ bias,
                         float* __restrict__ out,
                         int mode)
{
    __shared__ _Float16 patch[PROWS * PCOLS * PSTRIDE];  // 36992 B
    __shared__ float lg_arr[64 * LSTRIDE];               // 19456 B
    __shared__ float r_arr[64 * PXS];                    // 19456 B

    const int tid  = threadIdx.x;
    const int lane = tid & 63;
    const int w    = tid >> 6;     // 0..15
    const int c    = w & 7;        // output capsule
    const int g    = w >> 3;       // output row offset (0/1)
    const int l15  = lane & 15;    // A: f ; B & D: px-in-tile
    const int quad = lane >> 4;
    const int lane8 = lane * 8;

    const int bid = blockIdx.x & 511;   // probes replicate via grid 4096
    const int h2 = bid & 15, b = bid >> 4;
    const int h = h2 << 1;         // output rows h, h+1

    // ---- acc init (always, so mode=2 routing runs on zeros) ----
    f32x4 acc[2][8];
    #pragma unroll
    for (int mt = 0; mt < 2; ++mt)
        #pragma unroll
        for (int i = 0; i < 8; ++i) acc[mt][i] = (f32x4){0.f, 0.f, 0.f, 0.f};

    if (mode & 1) {
        // ---- stage input patch rows h-1..h+2, cols -1..32, fp16 ----
        const float4* x4 = (const float4*)x;
        for (int idx = tid; idx < PROWS * PCOLS * 32; idx += 1024) {
            int ch4  = idx & 31;
            int slot = idx >> 5;               // row*34 + colp
            int row  = slot / PCOLS;
            int colp = slot - row * PCOLS;
            int gh = h - 1 + row;
            int gw = colp - 1;
            float4 v = {0.f, 0.f, 0.f, 0.f};
            if ((unsigned)gh < 32u && (unsigned)gw < 32u)
                v = x4[(((b * 32 + gh) * 32 + gw) << 5) + ch4];
            _Float16 ph[4];
            ph[0] = (_Float16)v.x; ph[1] = (_Float16)v.y;
            ph[2] = (_Float16)v.z; ph[3] = (_Float16)v.w;
            *(ushort4*)&patch[slot * PSTRIDE + ch4 * 4] = *(const ushort4*)ph;
        }
        __syncthreads();

        // ---- B (patch) per-lane offsets: k = q*32+quad*8+j; tap = 2q+(quad>>1) ----
        int a_off[5];
        #pragma unroll
        for (int q = 0; q < 5; ++q) {
            int tap = 2 * q + (quad >> 1);
            if (tap > 8) tap = 8;                 // pad region: A is zero there
            int dy = tap / 3, dx = tap - dy * 3;
            a_off[q] = ((g + dy) * PCOLS + l15 + dx) * PSTRIDE + (quad & 1) * 8;
        }

        // ---- conv: 40 steps of (1 A b128, 2 B ds_read b128, 2 MFMA) ----
        #pragma unroll
        for (int q = 0; q < 5; ++q) {
            #pragma unroll
            for (int i = 0; i < 8; ++i) {
                int woff = ((i * 5 + q) * 8 + c) * 512 + lane8;
                fp16x8 aw = *(const fp16x8*)(w16 + woff);
                fp16x8 b0 = *(const fp16x8*)(patch + a_off[q] + i * 16);
                fp16x8 b1 = *(const fp16x8*)(patch + a_off[q] + 16 * PSTRIDE + i * 16);
                acc[0][i] = __builtin_amdgcn_mfma_f32_16x16x32_f16(aw, b0, acc[0][i], 0, 0, 0);
                acc[1][i] = __builtin_amdgcn_mfma_f32_16x16x32_f16(aw, b1, acc[1][i], 0, 0, 0);
            }
        }
    }

    if (!(mode & 2)) return;   // probe A ends here (acc runtime-dead, code live)

    // ---- dynamic routing: thread owns (slot = g*32+mt*16+l15, c, f = quad*4+0..3) ----
    const float4 bb4 = *(const float4*)(bias + c * 16 + quad * 4);
    const float barr[4] = {bb4.x, bb4.y, bb4.z, bb4.w};

    float actv[2][4];

    // iter 0: route = 1/8 uniform
    #pragma unroll
    for (int mt = 0; mt < 2; ++mt) {
        float pre[4];
        #pragma unroll
        for (int r = 0; r < 4; ++r) {
            float s = acc[mt][0][r] + acc[mt][1][r] + acc[mt][2][r] + acc[mt][3][r]
                    + acc[mt][4][r] + acc[mt][5][r] + acc[mt][6][r] + acc[mt][7][r];
            pre[r] = s * 0.125f + barr[r];
        }
        float s2 = sumquad(pre[0]*pre[0] + pre[1]*pre[1] + pre[2]*pre[2] + pre[3]*pre[3]);
        float scale = s2 * __builtin_amdgcn_rsqf(s2 + EPS) * __builtin_amdgcn_rcpf(1.f + s2);
        #pragma unroll
        for (int r = 0; r < 4; ++r) actv[mt][r] = scale * pre[r];
    }
    #pragma unroll
    for (int mt = 0; mt < 2; ++mt) {
        int slot = g * 32 + mt * 16 + l15;
        #pragma unroll
        for (int i = 0; i < 8; ++i) {
            float t = acc[mt][i][0]*actv[mt][0] + acc[mt][i][1]*actv[mt][1]
                    + acc[mt][i][2]*actv[mt][2] + acc[mt][i][3]*actv[mt][3];
            t = sumquad(t);
            if (quad == 0) lg_arr[slot * LSTRIDE + i * 9 + c] = t;
        }
    }
    __syncthreads();
    if (tid < 512) {   // softmax over c for each (slot, i): 64*8 = 512 tasks
        int p = tid >> 3, ii = tid & 7;
        const float* lrow = &lg_arr[p * LSTRIDE + ii * 9];
        float m = lrow[0];
        #pragma unroll
        for (int cc = 1; cc < 8; ++cc) m = fmaxf(m, lrow[cc]);
        float e[8]; float den = 0.f;
        #pragma unroll
        for (int cc = 0; cc < 8; ++cc) { e[cc] = __expf(lrow[cc] - m); den += e[cc]; }
        float rd = __builtin_amdgcn_rcpf(den);
        #pragma unroll
        for (int cc = 0; cc < 8; ++cc) r_arr[p * PXS + cc * 8 + ii] = e[cc] * rd;
    }
    __syncthreads();

    // iter 1
    #pragma unroll
    for (int mt = 0; mt < 2; ++mt) {
        int slot = g * 32 + mt * 16 + l15;
        const float4* rp = (const float4*)&r_arr[slot * PXS + c * 8];
        float4 r0 = rp[0], r1 = rp[1];
        float pre[4];
        #pragma unroll
        for (int r = 0; r < 4; ++r) {
            float s;
            s  = r0.x * acc[mt][0][r]; s = fmaf(r0.y, acc[mt][1][r], s);
            s  = fmaf(r0.z, acc[mt][2][r], s); s = fmaf(r0.w, acc[mt][3][r], s);
            s  = fmaf(r1.x, acc[mt][4][r], s); s = fmaf(r1.y, acc[mt][5][r], s);
            s  = fmaf(r1.z, acc[mt][6][r], s); s = fmaf(r1.w, acc[mt][7][r], s);
            pre[r] = s + barr[r];
        }
        float s2 = sumquad(pre[0]*pre[0] + pre[1]*pre[1] + pre[2]*pre[2] + pre[3]*pre[3]);
        float scale = s2 * __builtin_amdgcn_rsqf(s2 + EPS) * __builtin_amdgcn_rcpf(1.f + s2);
        #pragma unroll
        for (int r = 0; r < 4; ++r) actv[mt][r] = scale * pre[r];
    }
    #pragma unroll
    for (int mt = 0; mt < 2; ++mt) {
        int slot = g * 32 + mt * 16 + l15;
        #pragma unroll
        for (int i = 0; i < 8; ++i) {
            float t = acc[mt][i][0]*actv[mt][0] + acc[mt][i][1]*actv[mt][1]
                    + acc[mt][i][2]*actv[mt][2] + acc[mt][i][3]*actv[mt][3];
            t = sumquad(t);
            if (quad == 0) lg_arr[slot * LSTRIDE + i * 9 + c] += t;
        }
    }
    __syncthreads();
    if (tid < 512) {
        int p = tid >> 3, ii = tid & 7;
        const float* lrow = &lg_arr[p * LSTRIDE + ii * 9];
        float m = lrow[0];
        #pragma unroll
        for (int cc = 1; cc < 8; ++cc) m = fmaxf(m, lrow[cc]);
        float e[8]; float den = 0.f;
        #pragma unroll
        for (int cc = 0; cc < 8; ++cc) { e[cc] = __expf(lrow[cc] - m); den += e[cc]; }
        float rd = __builtin_amdgcn_rcpf(den);
        #pragma unroll
        for (int cc = 0; cc < 8; ++cc) r_arr[p * PXS + cc * 8 + ii] = e[cc] * rd;
    }
    __syncthreads();

    // iter 2: final activation -> out (per-lane float4: f = quad*4 + 0..3)
    #pragma unroll
    for (int mt = 0; mt < 2; ++mt) {
        int slot = g * 32 + mt * 16 + l15;
        const float4* rp = (const float4*)&r_arr[slot * PXS + c * 8];
        float4 r0 = rp[0], r1 = rp[1];
        float pre[4];
        #pragma unroll
        for (int r = 0; r < 4; ++r) {
            float s;
            s  = r0.x * acc[mt][0][r]; s = fmaf(r0.y, acc[mt][1][r], s);
            s  = fmaf(r0.z, acc[mt][2][r], s); s = fmaf(r0.w, acc[mt][3][r], s);
            s  = fmaf(r1.x, acc[mt][4][r], s); s = fmaf(r1.y, acc[mt][5][r], s);
            s  = fmaf(r1.z, acc[mt][6][r], s); s = fmaf(r1.w, acc[mt][7][r], s);
            pre[r] = s + barr[r];
        }
        float s2 = sumquad(pre[0]*pre[0] + pre[1]*pre[1] + pre[2]*pre[2] + pre[3]*pre[3]);
        float scale = s2 * __builtin_amdgcn_rsqf(s2 + EPS) * __builtin_amdgcn_rcpf(1.f + s2);
        float4 o4 = { scale*pre[0], scale*pre[1], scale*pre[2], scale*pre[3] };
        int gh = h + g;
        int px = mt * 16 + l15;
        *(float4*)(out + (((b * 32 + gh) * 32 + px) << 7) + c * 16 + quad * 4) = o4;
    }
}

extern "C" void kernel_launch(void* const* d_in, const int* in_sizes, int n_in,
                              void* d_out, int out_size, void* d_ws, size_t ws_size,
                              hipStream_t stream) {
    const float* x    = (const float*)d_in[0];
    const float* wts  = (const float*)d_in[1];
    const float* bias = (const float*)d_in[2];
    float* out        = (float*)d_out;
    _Float16* w16     = (_Float16*)d_ws;

    prep_weights<<<dim3(640), dim3(256), 0, stream>>>(wts, w16);
    // probe A: 8x (staging+conv), no routing, no stores
    capsule_mfma_kernel<<<dim3(4096), dim3(1024), 0, stream>>>(x, w16, bias, out, 1);
    // probe B: 8x (routing on zero acc); writes overwritten by the real pass
    capsule_mfma_kernel<<<dim3(4096), dim3(1024), 0, stream>>>(x, w16, bias, out, 2);
    // real kernel LAST -> correct output
    capsule_mfma_kernel<<<dim3(512), dim3(1024), 0, stream>>>(x, w16, bias, out, 3);
}

// Round 10
// 114.700 us; speedup vs baseline: 3.7533x; 3.0029x over previous
//
#include <hip/hip_runtime.h>
#include <math.h>

// Capsule conv + dynamic routing via fp16 MFMA (16x16x32), swapped operands:
// A = prepped fp16 weights (M = f), B = LDS input patch (N = px).
// R21: c-PAIR waves x ONE-ROUND (the untested matrix cell). R20's clean probe
// decomposed the fused 42us: staging+conv = 18.6us (MFMA only 4.7), routing =
// 11.6us, ~12us barrier/non-overlap exposure. Conv is LDS-issue-bound
// (2560 ds_read_b128/CU). Fix: block = 1024 thr = 16 waves =
// (c-pair 0..3) x (g 0..1) x (mt 0..1); each wave does ONE B ds_read per
// conv step shared by TWO capsules (2 A-loads, 2 MFMAs) -> per-CU conv
// ds_reads halve. acc = 2cc x 8i x f32x4 = 64 regs (same as R18); LDS 76KB,
// grid 512 = one round of 2 blocks/CU; staging/routing structure unchanged.
// R15 (c-pair, 4-round small blocks) was confounded; R18 (one-round) kept
// full B-redundancy - this isolates the B-sharing lever in the good geometry.
// NOTE: hipLaunchCooperativeKernel is NOT graph-capturable here (R7 failed);
// ~44us d_ws re-poison fill + ~12us restore/launch are fixed harness overhead.
//
// x:    [B=32][H=32][W=32][128] fp32 (128 = i*16+cin)
// wts:  [i=8][k=144][o=128] fp32 -> w16[(i*5+q)][c][lane][j]
//       = wts[(i*144 + q*32 + (lane>>4)*8 + j)*128 + c*16 + (lane&15)], 0 for k>=144
// out:  [B][H][W][128] fp32 (o = c*16+f)
//
// Block = 1024 = 16 waves; wave w: cp = w&3, g = (w>>2)&1, mt = w>>3.
// Grid = 512 (b*16 + h2), h = 2*h2. Wave's slot set: slot = g*32+mt*16+l15.
// MFMA 16x16x32: A[m=lane&15 -> f][k=quad*8+j], B[k][n=lane&15 -> px].
// D: f = quad*4 + reg; capsules c0=2cp, c0+1 share the B fragment.

typedef _Float16 fp16x8 __attribute__((ext_vector_type(8)));
typedef float f32x4 __attribute__((ext_vector_type(4)));

#define EPS 1e-7f
constexpr int PSTRIDE = 136;   // fp16 elems; 272B row stride: 16B-aligned, 2-way banks (free)
constexpr int PCOLS   = 34;    // 32 px + 2 halo
constexpr int PROWS   = 4;     // rows h-1..h+2
constexpr int LSTRIDE = 76;    // lg_arr: [slot*76 + i*9 + c]
constexpr int PXS     = 76;    // r_arr:  [slot*76 + c*8 + i]; b128 stride 304B -> 2-way (free)
constexpr int W_ELEMS = 40 * 8 * 64 * 8;   // 163840

// sum across the 4 quads (lanes ^16, ^32); all lanes receive the total
__device__ __forceinline__ float sumquad(float v) {
    v += __shfl_xor(v, 16);
    v += __shfl_xor(v, 32);
    return v;
}

// prep: direct scatter, 640 blocks x 256 threads, 1 element each (R8-proven).
__global__ __launch_bounds__(256)
void prep_weights(const float* __restrict__ wts,
                  _Float16* __restrict__ w16) {
    int n = blockIdx.x * 256 + threadIdx.x;        // 0..163839
    if (n >= W_ELEMS) return;
    int j    = n & 7;
    int ln   = (n >> 3) & 63;
    int c0   = (n >> 9) & 7;
    int iq   = n >> 12;                            // i*5+q
    int i0   = iq / 5;
    int q0   = iq - i0 * 5;
    int k = q0 * 32 + (ln >> 4) * 8 + j;
    float w = 0.f;
    if (k < 144) w = wts[(i0 * 144 + k) * 128 + c0 * 16 + (ln & 15)];
    w16[n] = (_Float16)w;                          // RNE
}

__global__ __launch_bounds__(1024, 4)
void capsule_mfma_kernel(const float* __restrict__ x,
                         const _Float16* __restrict__ w16,
                         const float* __restrict__ bias,
                         float* __restrict__ out)
{
    __shared__ _Float16 patch[PROWS * PCOLS * PSTRIDE];  // 36992 B
    __shared__ float lg_arr[64 * LSTRIDE];               // 19456 B
    __shared__ float r_arr[64 * PXS];                    // 19456 B

    const int tid  = threadIdx.x;
    const int lane = tid & 63;
    const int w    = tid >> 6;     // 0..15
    const int cp   = w & 3;        // capsule pair
    const int g    = (w >> 2) & 1; // output row offset
    const int mt   = w >> 3;       // px half
    const int c0   = 2 * cp;
    const int l15  = lane & 15;    // A: f ; B & D: px-in-tile
    const int quad = lane >> 4;
    const int lane8 = lane * 8;

    const int bid = blockIdx.x;
    const int h2 = bid & 15, b = bid >> 4;
    const int h = h2 << 1;         // output rows h, h+1

    // ---- stage input patch rows h-1..h+2, cols -1..32, fp16 ----
    const float4* x4 = (const float4*)x;
    for (int idx = tid; idx < PROWS * PCOLS * 32; idx += 1024) {
        int ch4  = idx & 31;
        int slot = idx >> 5;               // row*34 + colp
        int row  = slot / PCOLS;
        int colp = slot - row * PCOLS;
        int gh = h - 1 + row;
        int gw = colp - 1;
        float4 v = {0.f, 0.f, 0.f, 0.f};
        if ((unsigned)gh < 32u && (unsigned)gw < 32u)
            v = x4[(((b * 32 + gh) * 32 + gw) << 5) + ch4];
        _Float16 ph[4];
        ph[0] = (_Float16)v.x; ph[1] = (_Float16)v.y;
        ph[2] = (_Float16)v.z; ph[3] = (_Float16)v.w;
        *(ushort4*)&patch[slot * PSTRIDE + ch4 * 4] = *(const ushort4*)ph;
    }
    __syncthreads();

    // ---- B (patch) per-lane offsets: k = q*32 + quad*8 + j; tap = 2q+(quad>>1) ----
    // wave's pixels: row h+g, cols mt*16 + l15
    int a_off[5];
    #pragma unroll
    for (int q = 0; q < 5; ++q) {
        int tap = 2 * q + (quad >> 1);
        if (tap > 8) tap = 8;                 // pad region: A is zero there
        int dy = tap / 3, dx = tap - dy * 3;
        a_off[q] = ((g + dy) * PCOLS + mt * 16 + l15 + dx) * PSTRIDE + (quad & 1) * 8;
    }

    // ---- conv via MFMA: 40 steps of (2 A b128 from L1/L2, 1 B ds_read, 2 MFMA) ----
    f32x4 acc[2][8];
    #pragma unroll
    for (int cc = 0; cc < 2; ++cc)
        #pragma unroll
        for (int i = 0; i < 8; ++i) acc[cc][i] = (f32x4){0.f, 0.f, 0.f, 0.f};

    #pragma unroll
    for (int q = 0; q < 5; ++q) {
        #pragma unroll
        for (int i = 0; i < 8; ++i) {
            int woff = ((i * 5 + q) * 8 + c0) * 512 + lane8;
            fp16x8 a0 = *(const fp16x8*)(w16 + woff);
            fp16x8 a1 = *(const fp16x8*)(w16 + woff + 512);
            fp16x8 bb = *(const fp16x8*)(patch + a_off[q] + i * 16);
            acc[0][i] = __builtin_amdgcn_mfma_f32_16x16x32_f16(a0, bb, acc[0][i], 0, 0, 0);
            acc[1][i] = __builtin_amdgcn_mfma_f32_16x16x32_f16(a1, bb, acc[1][i], 0, 0, 0);
        }
    }

    // ---- dynamic routing: thread owns (slot, c in {c0,c0+1}, f = quad*4+0..3) ----
    const int slot = g * 32 + mt * 16 + l15;

    float barr[2][4];
    #pragma unroll
    for (int cc = 0; cc < 2; ++cc) {
        float4 bb4 = *(const float4*)(bias + (c0 + cc) * 16 + quad * 4);
        barr[cc][0] = bb4.x; barr[cc][1] = bb4.y; barr[cc][2] = bb4.z; barr[cc][3] = bb4.w;
    }

    float actv[2][4];

    // iter 0: route = 1/8 uniform
    #pragma unroll
    for (int cc = 0; cc < 2; ++cc) {
        float pre[4];
        #pragma unroll
        for (int r = 0; r < 4; ++r) {
            float s = acc[cc][0][r] + acc[cc][1][r] + acc[cc][2][r] + acc[cc][3][r]
                    + acc[cc][4][r] + acc[cc][5][r] + acc[cc][6][r] + acc[cc][7][r];
            pre[r] = s * 0.125f + barr[cc][r];
        }
        float s2 = sumquad(pre[0]*pre[0] + pre[1]*pre[1] + pre[2]*pre[2] + pre[3]*pre[3]);
        float scale = s2 * __builtin_amdgcn_rsqf(s2 + EPS) * __builtin_amdgcn_rcpf(1.f + s2);
        #pragma unroll
        for (int r = 0; r < 4; ++r) actv[cc][r] = scale * pre[r];
    }
    #pragma unroll
    for (int cc = 0; cc < 2; ++cc)
        #pragma unroll
        for (int i = 0; i < 8; ++i) {
            float t = acc[cc][i][0]*actv[cc][0] + acc[cc][i][1]*actv[cc][1]
                    + acc[cc][i][2]*actv[cc][2] + acc[cc][i][3]*actv[cc][3];
            t = sumquad(t);
            if (quad == 0) lg_arr[slot * LSTRIDE + i * 9 + (c0 + cc)] = t;
        }
    __syncthreads();
    if (tid < 512) {   // softmax over c for each (slot, i): 64*8 = 512 tasks
        int p = tid >> 3, ii = tid & 7;
        const float* lrow = &lg_arr[p * LSTRIDE + ii * 9];
        float m = lrow[0];
        #pragma unroll
        for (int cc = 1; cc < 8; ++cc) m = fmaxf(m, lrow[cc]);
        float e[8]; float den = 0.f;
        #pragma unroll
        for (int cc = 0; cc < 8; ++cc) { e[cc] = __expf(lrow[cc] - m); den += e[cc]; }
        float rd = __builtin_amdgcn_rcpf(den);
        #pragma unroll
        for (int cc = 0; cc < 8; ++cc) r_arr[p * PXS + cc * 8 + ii] = e[cc] * rd;
    }
    __syncthreads();

    // iter 1
    #pragma unroll
    for (int cc = 0; cc < 2; ++cc) {
        const float4* rp = (const float4*)&r_arr[slot * PXS + (c0 + cc) * 8];
        float4 r0 = rp[0], r1 = rp[1];
        float pre[4];
        #pragma unroll
        for (int r = 0; r < 4; ++r) {
            float s;
            s  = r0.x * acc[cc][0][r]; s = fmaf(r0.y, acc[cc][1][r], s);
            s  = fmaf(r0.z, acc[cc][2][r], s); s = fmaf(r0.w, acc[cc][3][r], s);
            s  = fmaf(r1.x, acc[cc][4][r], s); s = fmaf(r1.y, acc[cc][5][r], s);
            s  = fmaf(r1.z, acc[cc][6][r], s); s = fmaf(r1.w, acc[cc][7][r], s);
            pre[r] = s + barr[cc][r];
        }
        float s2 = sumquad(pre[0]*pre[0] + pre[1]*pre[1] + pre[2]*pre[2] + pre[3]*pre[3]);
        float scale = s2 * __builtin_amdgcn_rsqf(s2 + EPS) * __builtin_amdgcn_rcpf(1.f + s2);
        #pragma unroll
        for (int r = 0; r < 4; ++r) actv[cc][r] = scale * pre[r];
    }
    #pragma unroll
    for (int cc = 0; cc < 2; ++cc)
        #pragma unroll
        for (int i = 0; i < 8; ++i) {
            float t = acc[cc][i][0]*actv[cc][0] + acc[cc][i][1]*actv[cc][1]
                    + acc[cc][i][2]*actv[cc][2] + acc[cc][i][3]*actv[cc][3];
            t = sumquad(t);
            if (quad == 0) lg_arr[slot * LSTRIDE + i * 9 + (c0 + cc)] += t;
        }
    __syncthreads();
    if (tid < 512) {
        int p = tid >> 3, ii = tid & 7;
        const float* lrow = &lg_arr[p * LSTRIDE + ii * 9];
        float m = lrow[0];
        #pragma unroll
        for (int cc = 1; cc < 8; ++cc) m = fmaxf(m, lrow[cc]);
        float e[8]; float den = 0.f;
        #pragma unroll
        for (int cc = 0; cc < 8; ++cc) { e[cc] = __expf(lrow[cc] - m); den += e[cc]; }
        float rd = __builtin_amdgcn_rcpf(den);
        #pragma unroll
        for (int cc = 0; cc < 8; ++cc) r_arr[p * PXS + cc * 8 + ii] = e[cc] * rd;
    }
    __syncthreads();

    // iter 2: final activation -> out (per-lane float4: f = quad*4 + 0..3)
    #pragma unroll
    for (int cc = 0; cc < 2; ++cc) {
        const float4* rp = (const float4*)&r_arr[slot * PXS + (c0 + cc) * 8];
        float4 r0 = rp[0], r1 = rp[1];
        float pre[4];
        #pragma unroll
        for (int r = 0; r < 4; ++r) {
            float s;
            s  = r0.x * acc[cc][0][r]; s = fmaf(r0.y, acc[cc][1][r], s);
            s  = fmaf(r0.z, acc[cc][2][r], s); s = fmaf(r0.w, acc[cc][3][r], s);
            s  = fmaf(r1.x, acc[cc][4][r], s); s = fmaf(r1.y, acc[cc][5][r], s);
            s  = fmaf(r1.z, acc[cc][6][r], s); s = fmaf(r1.w, acc[cc][7][r], s);
            pre[r] = s + barr[cc][r];
        }
        float s2 = sumquad(pre[0]*pre[0] + pre[1]*pre[1] + pre[2]*pre[2] + pre[3]*pre[3]);
        float scale = s2 * __builtin_amdgcn_rsqf(s2 + EPS) * __builtin_amdgcn_rcpf(1.f + s2);
        float4 o4 = { scale*pre[0], scale*pre[1], scale*pre[2], scale*pre[3] };
        int gh = h + g;
        int px = mt * 16 + l15;
        *(float4*)(out + (((b * 32 + gh) * 32 + px) << 7) + (c0 + cc) * 16 + quad * 4) = o4;
    }
}

extern "C" void kernel_launch(void* const* d_in, const int* in_sizes, int n_in,
                              void* d_out, int out_size, void* d_ws, size_t ws_size,
                              hipStream_t stream) {
    const float* x    = (const float*)d_in[0];
    const float* wts  = (const float*)d_in[1];
    const float* bias = (const float*)d_in[2];
    float* out        = (float*)d_out;
    _Float16* w16     = (_Float16*)d_ws;

    prep_weights<<<dim3(640), dim3(256), 0, stream>>>(wts, w16);
    capsule_mfma_kernel<<<dim3(512), dim3(1024), 0, stream>>>(x, w16, bias, out);
}